// Round 3
// baseline (604.089 us; speedup 1.0000x reference)
//
#include <hip/hip_runtime.h>
#include <hip/hip_bf16.h>
#include <stdint.h>

typedef __hip_bfloat16 bf16;
typedef __hip_bfloat162 bf162;

// ---- table sizes (elements) ----
#define S0 ((size_t)(128*128*32))
#define S1 ((size_t)(256*256*32))
#define S2 ((size_t)(512*512*32))
#define LCN ((size_t)(64*64*64*32))

// ---- pre-pass tile bookkeeping: 64-position transpose tiles ----
#define T128 (128*128/64)            // 256
#define T256 (256*256/64)            // 1024
#define T512 (512*512/64)            // 4096
#define TPLANES (3*T128 + 3*T256 + 3*T512)   // 16128
#define TLC2 ((int)(LCN/2048))                // 4096 (256 thr x 8 elems)

// ---- spatial sort ----
#define NBUCKETS 32768               // 32^3 morton cells

// Spread 10 (we use 5) bits so there are 2 zero bits between each.
__device__ __forceinline__ uint32_t mpart(uint32_t x)
{
    x = (x | (x << 16)) & 0x030000FFu;
    x = (x | (x << 8))  & 0x0300F00Fu;
    x = (x | (x << 4))  & 0x030C30C3u;
    x = (x | (x << 2))  & 0x09249249u;
    return x;
}

__device__ __forceinline__ uint32_t bucket_of(float xn, float yn, float zn)
{
    float bx = fminf(fmaxf(floorf((xn + 1.0f) * 16.0f), 0.0f), 31.0f);
    float by = fminf(fmaxf(floorf((yn + 1.0f) * 16.0f), 0.0f), 31.0f);
    float bz = fminf(fmaxf(floorf((zn + 1.0f) * 16.0f), 0.0f), 31.0f);
    return mpart((uint32_t)bx) | (mpart((uint32_t)by) << 1) | (mpart((uint32_t)bz) << 2);
}

__device__ __forceinline__ uint32_t pack2(float a, float b)
{
    union { bf162 h; uint32_t u; } cv;
    cv.h = __halves2bfloat162(__float2bfloat16(a), __float2bfloat16(b));
    return cv.u;
}

// ---------------------------------------------------------------------------
// Zero the bucket counters (graph-capture-safe replacement for hipMemsetAsync).
// ---------------------------------------------------------------------------
__global__ __launch_bounds__(256) void zero_counts_kernel(unsigned int* __restrict__ counts)
{
    counts[blockIdx.x * 256 + threadIdx.x] = 0u;
}

// ---------------------------------------------------------------------------
// Fused pre-pass: 9 plane transposes ([32,HW] f32 -> [HW,32] bf16) + lc0 cast
// + per-bucket point histogram (for the spatial counting sort).
// Vectorized: float4 global loads, 16B packed-bf16 stores.
// ---------------------------------------------------------------------------
__global__ __launch_bounds__(256) void prepass_kernel(
    const float* __restrict__ p00, const float* __restrict__ p01, const float* __restrict__ p02,
    const float* __restrict__ p10, const float* __restrict__ p11, const float* __restrict__ p12,
    const float* __restrict__ p20, const float* __restrict__ p21, const float* __restrict__ p22,
    const float* __restrict__ lc0,
    bf16* __restrict__ tp0, bf16* __restrict__ tp1, bf16* __restrict__ tp2,
    bf16* __restrict__ lc0b,
    const float* __restrict__ pts, const float* __restrict__ aabb,
    unsigned int* __restrict__ counts, int N)
{
    const int b = blockIdx.x;
    const int tid = threadIdx.x;
    __shared__ float t[64 * 33];
    if (b < TPLANES) {
        const float* src; bf16* dst; int HW, tile;
        if (b < 3 * T128) {
            int pid = b >> 8; tile = b & (T128 - 1); HW = 128 * 128;
            src = pid == 0 ? p00 : (pid == 1 ? p01 : p02);
            dst = tp0 + (size_t)pid * S0;
        } else if (b < 3 * T128 + 3 * T256) {
            int bb = b - 3 * T128; int pid = bb >> 10; tile = bb & (T256 - 1); HW = 256 * 256;
            src = pid == 0 ? p10 : (pid == 1 ? p11 : p12);
            dst = tp1 + (size_t)pid * S1;
        } else {
            int bb = b - 3 * T128 - 3 * T256; int pid = bb >> 12; tile = bb & (T512 - 1); HW = 512 * 512;
            src = pid == 0 ? p20 : (pid == 1 ? p21 : p22);
            dst = tp2 + (size_t)pid * S2;
        }
        const int base = tile * 64;
        // read: 64 pos x 32 ch = 512 float4; 256 thr x 2
#pragma unroll
        for (int i = 0; i < 2; ++i) {
            int linear = i * 256 + tid;              // [0,512)
            int ch = linear >> 4, pq = linear & 15;  // pq = pos quad
            float4 v = *(const float4*)(src + (size_t)ch * HW + base + pq * 4);
            t[(pq * 4 + 0) * 33 + ch] = v.x;
            t[(pq * 4 + 1) * 33 + ch] = v.y;
            t[(pq * 4 + 2) * 33 + ch] = v.z;
            t[(pq * 4 + 3) * 33 + ch] = v.w;
        }
        __syncthreads();
        // write: each thread packs 8 channels of one position into 16B
        {
            int pos = tid >> 2, chunk = tid & 3;
            const float* row = t + pos * 33 + chunk * 8;
            uint4 o;
            o.x = pack2(row[0], row[1]);
            o.y = pack2(row[2], row[3]);
            o.z = pack2(row[4], row[5]);
            o.w = pack2(row[6], row[7]);
            *(uint4*)(dst + (size_t)(base + pos) * 32 + chunk * 8) = o;
        }
    } else if (b < TPLANES + TLC2) {
        size_t off = (size_t)(b - TPLANES) * 2048 + (size_t)tid * 8;
        float4 v0 = *(const float4*)(lc0 + off);
        float4 v1 = *(const float4*)(lc0 + off + 4);
        uint4 o;
        o.x = pack2(v0.x, v0.y);
        o.y = pack2(v0.z, v0.w);
        o.z = pack2(v1.x, v1.y);
        o.w = pack2(v1.z, v1.w);
        *(uint4*)(lc0b + off) = o;
    } else {
        int idx = (b - TPLANES - TLC2) * 256 + tid;
        if (idx < N) {
            float px = pts[3 * (size_t)idx + 0];
            float py = pts[3 * (size_t)idx + 1];
            float pz = pts[3 * (size_t)idx + 2];
            float xn = (px - aabb[0]) * (2.0f / (aabb[3] - aabb[0])) - 1.0f;
            float yn = (py - aabb[1]) * (2.0f / (aabb[4] - aabb[1])) - 1.0f;
            float zn = (pz - aabb[2]) * (2.0f / (aabb[5] - aabb[2])) - 1.0f;
            atomicAdd(&counts[bucket_of(xn, yn, zn)], 1u);
        }
    }
}

// ---------------------------------------------------------------------------
// Exclusive prefix sum over NBUCKETS=32768 counters, single block.
// ---------------------------------------------------------------------------
__global__ __launch_bounds__(1024) void scan_kernel(unsigned int* __restrict__ counts)
{
    __shared__ unsigned int sums[1024];
    const int t = threadIdx.x;
    unsigned int local[32];
    unsigned int s = 0;
#pragma unroll
    for (int i = 0; i < 32; ++i) { local[i] = counts[t * 32 + i]; s += local[i]; }
    sums[t] = s;
    __syncthreads();
    for (int off = 1; off < 1024; off <<= 1) {
        unsigned int v = (t >= off) ? sums[t - off] : 0u;
        __syncthreads();
        sums[t] += v;
        __syncthreads();
    }
    unsigned int run = sums[t] - s;                  // exclusive base for this chunk
#pragma unroll
    for (int i = 0; i < 32; ++i) { unsigned int c = local[i]; counts[t * 32 + i] = run; run += c; }
}

// ---------------------------------------------------------------------------
// Scatter pass: place each point into its bucket slot, pre-normalized.
// sp[pos] = (xn, yn, zn, bitcast(n)).  Destroys the offsets array.
// ---------------------------------------------------------------------------
__global__ __launch_bounds__(256) void scatter_kernel(
    const float* __restrict__ pts, const float* __restrict__ aabb,
    unsigned int* __restrict__ offsets, float4* __restrict__ sp, int N)
{
    int n = blockIdx.x * 256 + threadIdx.x;
    if (n >= N) return;
    float px = pts[3 * (size_t)n + 0];
    float py = pts[3 * (size_t)n + 1];
    float pz = pts[3 * (size_t)n + 2];
    float xn = (px - aabb[0]) * (2.0f / (aabb[3] - aabb[0])) - 1.0f;
    float yn = (py - aabb[1]) * (2.0f / (aabb[4] - aabb[1])) - 1.0f;
    float zn = (pz - aabb[2]) * (2.0f / (aabb[5] - aabb[2])) - 1.0f;
    unsigned int pos = atomicAdd(&offsets[bucket_of(xn, yn, zn)], 1u);
    float4 v; v.x = xn; v.y = yn; v.z = zn; v.w = __int_as_float(n);
    sp[pos] = v;
}

// ---------------------------------------------------------------------------
// Bilinear sample from transposed bf16 plane [H, W, 32]; literal R.
// int32 indexing (max index 512*512*16 = 4.2M, fits easily).
// ---------------------------------------------------------------------------
template <int R>
__device__ __forceinline__ float2 sample_tp(const bf162* __restrict__ tp,
                                            float cx, float cy, int cpair)
{
    float gx = (cx + 1.0f) * (0.5f * (float)(R - 1));
    float gy = (cy + 1.0f) * (0.5f * (float)(R - 1));
    float fx = fminf(fmaxf(floorf(gx), 0.0f), (float)(R - 2));
    float fy = fminf(fmaxf(floorf(gy), 0.0f), (float)(R - 2));
    float wx = gx - fx, wy = gy - fy;
    int ix = (int)fx, iy = (int)fy;
    int i00 = (iy * R + ix) * 16 + cpair;
    int i10 = i00 + R * 16;
    bf162 v00 = tp[i00];
    bf162 v01 = tp[i00 + 16];
    bf162 v10 = tp[i10];
    bf162 v11 = tp[i10 + 16];
    float w11 = wx * wy;
    float w01 = wx - w11;
    float w10 = wy - w11;
    float w00 = 1.0f - wx - wy + w11;
    float2 r;
    r.x = __bfloat162float(v00.x) * w00 + __bfloat162float(v01.x) * w01
        + __bfloat162float(v10.x) * w10 + __bfloat162float(v11.x) * w11;
    r.y = __bfloat162float(v00.y) * w00 + __bfloat162float(v01.y) * w01
        + __bfloat162float(v10.y) * w10 + __bfloat162float(v11.y) * w11;
    return r;
}

template <int R>
__device__ __forceinline__ float2 plane_feat(const bf162* __restrict__ tp,
                                             float xn, float yn, float zn, int cpair)
{
    const int ps = R * R * 16;                       // one plane in bf162 units
    float2 a = sample_tp<R>(tp,          xn, yn, cpair);  // comb (0,1)
    float2 b = sample_tp<R>(tp + ps,     xn, zn, cpair);  // comb (0,2)
    float2 c = sample_tp<R>(tp + 2 * ps, yn, zn, cpair);  // comb (1,2)
    float2 r; r.x = a.x * b.x * c.x; r.y = a.y * b.y * c.y;
    return r;
}

// Fallback sampler on original f32 [32,H,W] layout
__device__ __forceinline__ float2 sample_f32(const float* __restrict__ pl, int R,
                                             float cx, float cy, int ch)
{
    float gx = (cx + 1.0f) * 0.5f * (float)(R - 1);
    float gy = (cy + 1.0f) * 0.5f * (float)(R - 1);
    float fx = fminf(fmaxf(floorf(gx), 0.0f), (float)(R - 2));
    float fy = fminf(fmaxf(floorf(gy), 0.0f), (float)(R - 2));
    float wx = gx - fx, wy = gy - fy;
    int ix = (int)fx, iy = (int)fy;
    float w11 = wx * wy, w01 = wx - w11, w10 = wy - w11, w00 = 1.0f - wx - wy + w11;
    size_t HW = (size_t)R * R;
    const float* q0 = pl + (size_t)ch * HW + (size_t)iy * R + ix;
    const float* q1 = q0 + HW;
    float2 r;
    r.x = q0[0] * w00 + q0[1] * w01 + q0[R] * w10 + q0[R + 1] * w11;
    r.y = q1[0] * w00 + q1[1] * w01 + q1[R] * w10 + q1[R + 1] * w11;
    return r;
}

// ---------------------------------------------------------------------------
// RBF feature pair, fast rcp.  int32 indexing on the TP path.
// ---------------------------------------------------------------------------
template <bool TP>
__device__ __forceinline__ float2 rbf_feat(const bf162* __restrict__ lc0b,
                                           const float* __restrict__ lc0f,
                                           const float* __restrict__ ks,
                                           float xn, float yn, float zn, int cpair)
{
    const float interval = 2.0f / 63.0f;
    const float invi = 31.5f;
    float fc0 = fminf(fmaxf(floorf((xn + 1.0f) * invi), 0.0f), 62.0f);
    float fc1 = fminf(fmaxf(floorf((yn + 1.0f) * invi), 0.0f), 62.0f);
    float fc2 = fminf(fmaxf(floorf((zn + 1.0f) * invi), 0.0f), 62.0f);
    int c0 = (int)fc0, c1 = (int)fc1, c2 = (int)fc2;
    float dx0 = xn - (-1.0f + fc0 * interval), dx1 = dx0 - interval;
    float dy0 = yn - (-1.0f + fc1 * interval), dy1 = dy0 - interval;
    float dz0 = zn - (-1.0f + fc2 * interval), dz1 = dz0 - interval;
    int ibase = (c0 * 64 + c1) * 64 + c2;

    float phi[8]; int id[8];
    float sum = 0.0f;
#pragma unroll
    for (int k = 0; k < 8; ++k) {
        int i = (k >> 2) & 1, j = (k >> 1) & 1, l = k & 1;
        int idx = ibase + i * 4096 + j * 64 + l;
        id[k] = idx;
        float ddx = i ? dx1 : dx0;
        float ddy = j ? dy1 : dy0;
        float ddz = l ? dz1 : dz0;
        float dd = ddx * ddx + ddy * ddy + ddz * ddz;
        float s = ks[idx];
        float ph = __builtin_amdgcn_rcpf(fmaf(dd, s * s, 1.0f));
        phi[k] = ph;
        sum += ph;
    }
    float inv = __builtin_amdgcn_rcpf(sum + 1e-8f);
    float ax = 0.0f, ay = 0.0f;
#pragma unroll
    for (int k = 0; k < 8; ++k) {
        float w = phi[k] * inv;
        float vx, vy;
        if (TP) {
            bf162 v = lc0b[id[k] * 16 + cpair];
            vx = __bfloat162float(v.x); vy = __bfloat162float(v.y);
        } else {
            const float* cp = lc0f + (size_t)id[k] * 32 + 2 * cpair;
            vx = cp[0]; vy = cp[1];
        }
        ax = fmaf(w, vx, ax);
        ay = fmaf(w, vy, ay);
    }
    float2 r; r.x = ax; r.y = ay;
    return r;
}

// ---------------------------------------------------------------------------
// Main kernel: block = 4 waves = 4 points. Wave role is UNIFORM:
//   wave 0: scale 0 (R=128), wave 1: scale 1 (R=256), wave 2: scale 2 (R=512),
//   wave 3: RBF. Within a wave: lane = point(2b)*16 + cpair.
// SORTED: points come pre-normalized in morton order via sp[]; block index is
// XCD-chunk swizzled so each XCD walks a contiguous spatial range.
// ---------------------------------------------------------------------------
template <bool TP, bool SORTED>
__global__ __launch_bounds__(256) void field_kernel(
    const float* __restrict__ pts, const float* __restrict__ aabb,
    const float* __restrict__ p00, const float* __restrict__ p01, const float* __restrict__ p02,
    const float* __restrict__ p10, const float* __restrict__ p11, const float* __restrict__ p12,
    const float* __restrict__ p20, const float* __restrict__ p21, const float* __restrict__ p22,
    const bf162* __restrict__ tp0, const bf162* __restrict__ tp1, const bf162* __restrict__ tp2,
    const bf162* __restrict__ lc0b, const float* __restrict__ lc0f,
    const float* __restrict__ ks, const float* __restrict__ kpb,
    const float4* __restrict__ sp,
    float* __restrict__ out, int N)
{
    const int wave  = threadIdx.x >> 6;
    const int lane  = threadIdx.x & 63;
    const int p     = lane >> 4;
    const int cpair = lane & 15;
    int bid = blockIdx.x;
    if (SORTED) {
        int nb = gridDim.x;
        if ((nb & 7) == 0) bid = (bid & 7) * (nb >> 3) + (bid >> 3);  // XCD chunking
    }
    const int m = bid * 4 + p;
    if (m >= N) return;

    float xn, yn, zn;
    int n;
    if (SORTED) {
        float4 q = sp[m];
        xn = q.x; yn = q.y; zn = q.z; n = __float_as_int(q.w);
    } else {
        n = m;
        float px = pts[3 * (size_t)n + 0];
        float py = pts[3 * (size_t)n + 1];
        float pz = pts[3 * (size_t)n + 2];
        xn = (px - aabb[0]) * (2.0f / (aabb[3] - aabb[0])) - 1.0f;
        yn = (py - aabb[1]) * (2.0f / (aabb[4] - aabb[1])) - 1.0f;
        zn = (pz - aabb[2]) * (2.0f / (aabb[5] - aabb[2])) - 1.0f;
    }

    float2 val;
    int f;
    if (wave == 0) {
        if (TP) val = plane_feat<128>(tp0, xn, yn, zn, cpair);
        else {
            float2 a = sample_f32(p00, 128, xn, yn, 2 * cpair);
            float2 b = sample_f32(p01, 128, xn, zn, 2 * cpair);
            float2 c = sample_f32(p02, 128, yn, zn, 2 * cpair);
            val.x = a.x * b.x * c.x; val.y = a.y * b.y * c.y;
        }
        f = 2 * cpair;
    } else if (wave == 1) {
        if (TP) val = plane_feat<256>(tp1, xn, yn, zn, cpair);
        else {
            float2 a = sample_f32(p10, 256, xn, yn, 2 * cpair);
            float2 b = sample_f32(p11, 256, xn, zn, 2 * cpair);
            float2 c = sample_f32(p12, 256, yn, zn, 2 * cpair);
            val.x = a.x * b.x * c.x; val.y = a.y * b.y * c.y;
        }
        f = 32 + 2 * cpair;
    } else if (wave == 2) {
        if (TP) val = plane_feat<512>(tp2, xn, yn, zn, cpair);
        else {
            float2 a = sample_f32(p20, 512, xn, yn, 2 * cpair);
            float2 b = sample_f32(p21, 512, xn, zn, 2 * cpair);
            float2 c = sample_f32(p22, 512, yn, zn, 2 * cpair);
            val.x = a.x * b.x * c.x; val.y = a.y * b.y * c.y;
        }
        f = 64 + 2 * cpair;
    } else {
        val = rbf_feat<TP>(lc0b, lc0f, ks, xn, yn, zn, cpair);
        f = 96 + 2 * cpair;
    }

    val.x += kpb[f];
    val.y += kpb[f + 1];
    *(float2*)(out + (size_t)n * 128 + f) = val;
}

// ---------------------------------------------------------------------------
extern "C" void kernel_launch(void* const* d_in, const int* in_sizes, int n_in,
                              void* d_out, int out_size, void* d_ws, size_t ws_size,
                              hipStream_t stream)
{
    const float* pts  = (const float*)d_in[0];
    const float* aabb = (const float*)d_in[1];
    const float* pl[9];
    for (int i = 0; i < 9; ++i) pl[i] = (const float*)d_in[2 + i];
    const float* lc0 = (const float*)d_in[11];
    const float* ks  = (const float*)d_in[12];
    const float* kpb = (const float*)d_in[13];
    float* out = (float*)d_out;
    const int N = in_sizes[0] / 3;

    const size_t needTP = (3 * (S0 + S1 + S2) + LCN) * sizeof(bf16);   // 82.8 MB
    const size_t cntOff = needTP;                                      // 16B aligned
    const size_t spOff  = cntOff + (size_t)NBUCKETS * 4;               // 16B aligned
    const size_t needSort = spOff + (size_t)N * 16;

    bf16* w    = (bf16*)d_ws;
    bf16* tp0  = w;
    bf16* tp1  = tp0 + 3 * S0;
    bf16* tp2  = tp1 + 3 * S1;
    bf16* lc0b = tp2 + 3 * S2;
    unsigned int* counts = (unsigned int*)((char*)d_ws + cntOff);
    float4* sp = (float4*)((char*)d_ws + spOff);

    const bool useTP   = (d_ws != nullptr) && (ws_size >= needTP);
    const bool useSort = (d_ws != nullptr) && (ws_size >= needSort);
    const int blocks = (N + 3) / 4;
    const int cntBlocks = (N + 255) / 256;

    if (useSort) {
        zero_counts_kernel<<<NBUCKETS / 256, 256, 0, stream>>>(counts);
        prepass_kernel<<<TPLANES + TLC2 + cntBlocks, 256, 0, stream>>>(
            pl[0], pl[1], pl[2], pl[3], pl[4], pl[5], pl[6], pl[7], pl[8],
            lc0, tp0, tp1, tp2, lc0b, pts, aabb, counts, N);
        scan_kernel<<<1, 1024, 0, stream>>>(counts);
        scatter_kernel<<<cntBlocks, 256, 0, stream>>>(pts, aabb, counts, sp, N);
        field_kernel<true, true><<<blocks, 256, 0, stream>>>(
            pts, aabb, pl[0], pl[1], pl[2], pl[3], pl[4], pl[5], pl[6], pl[7], pl[8],
            (const bf162*)tp0, (const bf162*)tp1, (const bf162*)tp2,
            (const bf162*)lc0b, lc0, ks, kpb, sp, out, N);
    } else if (useTP) {
        prepass_kernel<<<TPLANES + TLC2, 256, 0, stream>>>(
            pl[0], pl[1], pl[2], pl[3], pl[4], pl[5], pl[6], pl[7], pl[8],
            lc0, tp0, tp1, tp2, lc0b, pts, aabb, nullptr, 0);
        field_kernel<true, false><<<blocks, 256, 0, stream>>>(
            pts, aabb, pl[0], pl[1], pl[2], pl[3], pl[4], pl[5], pl[6], pl[7], pl[8],
            (const bf162*)tp0, (const bf162*)tp1, (const bf162*)tp2,
            (const bf162*)lc0b, lc0, ks, kpb, nullptr, out, N);
    } else {
        field_kernel<false, false><<<blocks, 256, 0, stream>>>(
            pts, aabb, pl[0], pl[1], pl[2], pl[3], pl[4], pl[5], pl[6], pl[7], pl[8],
            (const bf162*)d_ws, (const bf162*)d_ws, (const bf162*)d_ws,
            (const bf162*)d_ws, lc0, ks, kpb, nullptr, out, N);
    }
}

// Round 4
// 587.148 us; speedup vs baseline: 1.0289x; 1.0289x over previous
//
#include <hip/hip_runtime.h>
#include <hip/hip_bf16.h>
#include <stdint.h>

typedef __hip_bfloat16 bf16;
typedef __hip_bfloat162 bf162;

// ---- table sizes (elements) ----
#define S0 ((size_t)(128*128*32))
#define S1 ((size_t)(256*256*32))
#define S2 ((size_t)(512*512*32))
#define LCN ((size_t)(64*64*64*32))

// ---- pre-pass tile bookkeeping: 64-position transpose tiles ----
#define T128 (128*128/64)            // 256
#define T256 (256*256/64)            // 1024
#define T512 (512*512/64)            // 4096
#define TPLANES (3*T128 + 3*T256 + 3*T512)   // 16128
#define TLC2 ((int)(LCN/2048))                // 4096 (256 thr x 8 elems)

// ---- spatial sort ----
#define NBUCKETS 32768               // 32^3 morton cells

__device__ __forceinline__ uint32_t mpart(uint32_t x)
{
    x = (x | (x << 16)) & 0x030000FFu;
    x = (x | (x << 8))  & 0x0300F00Fu;
    x = (x | (x << 4))  & 0x030C30C3u;
    x = (x | (x << 2))  & 0x09249249u;
    return x;
}

__device__ __forceinline__ uint32_t bucket_of(float xn, float yn, float zn)
{
    float bx = fminf(fmaxf(floorf((xn + 1.0f) * 16.0f), 0.0f), 31.0f);
    float by = fminf(fmaxf(floorf((yn + 1.0f) * 16.0f), 0.0f), 31.0f);
    float bz = fminf(fmaxf(floorf((zn + 1.0f) * 16.0f), 0.0f), 31.0f);
    return mpart((uint32_t)bx) | (mpart((uint32_t)by) << 1) | (mpart((uint32_t)bz) << 2);
}

__device__ __forceinline__ uint32_t pack2(float a, float b)
{
    union { bf162 h; uint32_t u; } cv;
    cv.h = __halves2bfloat162(__float2bfloat16(a), __float2bfloat16(b));
    return cv.u;
}

__device__ __forceinline__ void unpack8(uint4 u, float* f)
{
    const bf162* h = (const bf162*)&u;
    f[0] = __bfloat162float(h[0].x); f[1] = __bfloat162float(h[0].y);
    f[2] = __bfloat162float(h[1].x); f[3] = __bfloat162float(h[1].y);
    f[4] = __bfloat162float(h[2].x); f[5] = __bfloat162float(h[2].y);
    f[6] = __bfloat162float(h[3].x); f[7] = __bfloat162float(h[3].y);
}

// ---------------------------------------------------------------------------
__global__ __launch_bounds__(256) void zero_counts_kernel(unsigned int* __restrict__ counts)
{
    counts[blockIdx.x * 256 + threadIdx.x] = 0u;
}

// ---------------------------------------------------------------------------
// Plane transpose: [32,HW] f32 -> [HW,32] bf16 (split out for profiling).
// ---------------------------------------------------------------------------
__global__ __launch_bounds__(256) void transpose_kernel(
    const float* __restrict__ p00, const float* __restrict__ p01, const float* __restrict__ p02,
    const float* __restrict__ p10, const float* __restrict__ p11, const float* __restrict__ p12,
    const float* __restrict__ p20, const float* __restrict__ p21, const float* __restrict__ p22,
    bf16* __restrict__ tp0, bf16* __restrict__ tp1, bf16* __restrict__ tp2)
{
    const int b = blockIdx.x;
    const int tid = threadIdx.x;
    __shared__ float t[64 * 33];
    const float* src; bf16* dst; int HW, tile;
    if (b < 3 * T128) {
        int pid = b >> 8; tile = b & (T128 - 1); HW = 128 * 128;
        src = pid == 0 ? p00 : (pid == 1 ? p01 : p02);
        dst = tp0 + (size_t)pid * S0;
    } else if (b < 3 * T128 + 3 * T256) {
        int bb = b - 3 * T128; int pid = bb >> 10; tile = bb & (T256 - 1); HW = 256 * 256;
        src = pid == 0 ? p10 : (pid == 1 ? p11 : p12);
        dst = tp1 + (size_t)pid * S1;
    } else {
        int bb = b - 3 * T128 - 3 * T256; int pid = bb >> 12; tile = bb & (T512 - 1); HW = 512 * 512;
        src = pid == 0 ? p20 : (pid == 1 ? p21 : p22);
        dst = tp2 + (size_t)pid * S2;
    }
    const int base = tile * 64;
#pragma unroll
    for (int i = 0; i < 2; ++i) {
        int linear = i * 256 + tid;              // [0,512)
        int ch = linear >> 4, pq = linear & 15;  // pq = pos quad
        float4 v = *(const float4*)(src + (size_t)ch * HW + base + pq * 4);
        t[(pq * 4 + 0) * 33 + ch] = v.x;
        t[(pq * 4 + 1) * 33 + ch] = v.y;
        t[(pq * 4 + 2) * 33 + ch] = v.z;
        t[(pq * 4 + 3) * 33 + ch] = v.w;
    }
    __syncthreads();
    {
        int pos = tid >> 2, chunk = tid & 3;
        const float* row = t + pos * 33 + chunk * 8;
        uint4 o;
        o.x = pack2(row[0], row[1]);
        o.y = pack2(row[2], row[3]);
        o.z = pack2(row[4], row[5]);
        o.w = pack2(row[6], row[7]);
        *(uint4*)(dst + (size_t)(base + pos) * 32 + chunk * 8) = o;
    }
}

// ---------------------------------------------------------------------------
// lc0 f32 -> bf16 cast (split out for profiling).
// ---------------------------------------------------------------------------
__global__ __launch_bounds__(256) void lc0cast_kernel(
    const float* __restrict__ lc0, bf16* __restrict__ lc0b)
{
    size_t off = (size_t)blockIdx.x * 2048 + (size_t)threadIdx.x * 8;
    float4 v0 = *(const float4*)(lc0 + off);
    float4 v1 = *(const float4*)(lc0 + off + 4);
    uint4 o;
    o.x = pack2(v0.x, v0.y);
    o.y = pack2(v0.z, v0.w);
    o.z = pack2(v1.x, v1.y);
    o.w = pack2(v1.z, v1.w);
    *(uint4*)(lc0b + off) = o;
}

// ---------------------------------------------------------------------------
// Histogram: 4 points per thread via 3x float4 loads.
// ---------------------------------------------------------------------------
__global__ __launch_bounds__(256) void hist_kernel(
    const float* __restrict__ pts, const float* __restrict__ aabb,
    unsigned int* __restrict__ counts, int N)
{
    int g = blockIdx.x * 256 + threadIdx.x;
    int b0 = g * 4;
    if (b0 >= N) return;
    float a0 = aabb[0], a1 = aabb[1], a2 = aabb[2];
    float sx = 2.0f / (aabb[3] - a0);
    float sy = 2.0f / (aabb[4] - a1);
    float sz = 2.0f / (aabb[5] - a2);
    if (b0 + 3 < N) {
        const float4* p4 = (const float4*)(pts + (size_t)b0 * 3);
        float4 A = p4[0], B = p4[1], C = p4[2];
        float px[4] = {A.x, A.w, B.z, C.y};
        float py[4] = {A.y, B.x, B.w, C.z};
        float pz[4] = {A.z, B.y, C.x, C.w};
#pragma unroll
        for (int k = 0; k < 4; ++k) {
            float xn = (px[k] - a0) * sx - 1.0f;
            float yn = (py[k] - a1) * sy - 1.0f;
            float zn = (pz[k] - a2) * sz - 1.0f;
            atomicAdd(&counts[bucket_of(xn, yn, zn)], 1u);
        }
    } else {
        for (int i = b0; i < N; ++i) {
            float xn = (pts[3 * (size_t)i + 0] - a0) * sx - 1.0f;
            float yn = (pts[3 * (size_t)i + 1] - a1) * sy - 1.0f;
            float zn = (pts[3 * (size_t)i + 2] - a2) * sz - 1.0f;
            atomicAdd(&counts[bucket_of(xn, yn, zn)], 1u);
        }
    }
}

// ---------------------------------------------------------------------------
// Exclusive prefix sum over NBUCKETS=32768 counters, single block.
// ---------------------------------------------------------------------------
__global__ __launch_bounds__(1024) void scan_kernel(unsigned int* __restrict__ counts)
{
    __shared__ unsigned int sums[1024];
    const int t = threadIdx.x;
    unsigned int local[32];
    unsigned int s = 0;
#pragma unroll
    for (int i = 0; i < 32; ++i) { local[i] = counts[t * 32 + i]; s += local[i]; }
    sums[t] = s;
    __syncthreads();
    for (int off = 1; off < 1024; off <<= 1) {
        unsigned int v = (t >= off) ? sums[t - off] : 0u;
        __syncthreads();
        sums[t] += v;
        __syncthreads();
    }
    unsigned int run = sums[t] - s;                  // exclusive base for this chunk
#pragma unroll
    for (int i = 0; i < 32; ++i) { unsigned int c = local[i]; counts[t * 32 + i] = run; run += c; }
}

// ---------------------------------------------------------------------------
// Scatter: 4 points per thread; sp[pos] = (xn, yn, zn, bitcast(n)).
// ---------------------------------------------------------------------------
__global__ __launch_bounds__(256) void scatter_kernel(
    const float* __restrict__ pts, const float* __restrict__ aabb,
    unsigned int* __restrict__ offsets, float4* __restrict__ sp, int N)
{
    int g = blockIdx.x * 256 + threadIdx.x;
    int b0 = g * 4;
    if (b0 >= N) return;
    float a0 = aabb[0], a1 = aabb[1], a2 = aabb[2];
    float sx = 2.0f / (aabb[3] - a0);
    float sy = 2.0f / (aabb[4] - a1);
    float sz = 2.0f / (aabb[5] - a2);
    if (b0 + 3 < N) {
        const float4* p4 = (const float4*)(pts + (size_t)b0 * 3);
        float4 A = p4[0], B = p4[1], C = p4[2];
        float px[4] = {A.x, A.w, B.z, C.y};
        float py[4] = {A.y, B.x, B.w, C.z};
        float pz[4] = {A.z, B.y, C.x, C.w};
#pragma unroll
        for (int k = 0; k < 4; ++k) {
            float xn = (px[k] - a0) * sx - 1.0f;
            float yn = (py[k] - a1) * sy - 1.0f;
            float zn = (pz[k] - a2) * sz - 1.0f;
            unsigned int pos = atomicAdd(&offsets[bucket_of(xn, yn, zn)], 1u);
            float4 v; v.x = xn; v.y = yn; v.z = zn; v.w = __int_as_float(b0 + k);
            sp[pos] = v;
        }
    } else {
        for (int i = b0; i < N; ++i) {
            float xn = (pts[3 * (size_t)i + 0] - a0) * sx - 1.0f;
            float yn = (pts[3 * (size_t)i + 1] - a1) * sy - 1.0f;
            float zn = (pts[3 * (size_t)i + 2] - a2) * sz - 1.0f;
            unsigned int pos = atomicAdd(&offsets[bucket_of(xn, yn, zn)], 1u);
            float4 v; v.x = xn; v.y = yn; v.z = zn; v.w = __int_as_float(i);
            sp[pos] = v;
        }
    }
}

// ---------------------------------------------------------------------------
// New main kernel helpers: 16 points/wave, 8 channels/lane, 16B corner gathers.
// Texel row = 32ch bf16 = 64B = 4x uint4.  Lane cq in [0,4) reads uint4 #cq.
// ---------------------------------------------------------------------------
template <int R>
__device__ __forceinline__ void sample_tp16(const uint4* __restrict__ tq,
                                            float cx, float cy, int cq, float* o)
{
    float gx = (cx + 1.0f) * (0.5f * (float)(R - 1));
    float gy = (cy + 1.0f) * (0.5f * (float)(R - 1));
    float fx = fminf(fmaxf(floorf(gx), 0.0f), (float)(R - 2));
    float fy = fminf(fmaxf(floorf(gy), 0.0f), (float)(R - 2));
    float wx = gx - fx, wy = gy - fy;
    int ix = (int)fx, iy = (int)fy;
    int t00 = (iy * R + ix) * 4 + cq;
    uint4 u00 = tq[t00];
    uint4 u01 = tq[t00 + 4];
    uint4 u10 = tq[t00 + R * 4];
    uint4 u11 = tq[t00 + R * 4 + 4];
    float w11 = wx * wy;
    float w01 = wx - w11;
    float w10 = wy - w11;
    float w00 = 1.0f - wx - wy + w11;
    float a[8], b[8], c[8], d[8];
    unpack8(u00, a); unpack8(u01, b); unpack8(u10, c); unpack8(u11, d);
#pragma unroll
    for (int j = 0; j < 8; ++j)
        o[j] = a[j] * w00 + b[j] * w01 + c[j] * w10 + d[j] * w11;
}

template <int R>
__device__ __forceinline__ void plane_feat16(const uint4* __restrict__ tq,
                                             float xn, float yn, float zn, int cq, float* acc)
{
    const int ps = R * R * 4;                        // one plane in uint4 units
    float t0[8];
    sample_tp16<R>(tq,          xn, yn, cq, acc);    // comb (0,1)
    sample_tp16<R>(tq + ps,     xn, zn, cq, t0);     // comb (0,2)
#pragma unroll
    for (int j = 0; j < 8; ++j) acc[j] *= t0[j];
    sample_tp16<R>(tq + 2 * ps, yn, zn, cq, t0);     // comb (1,2)
#pragma unroll
    for (int j = 0; j < 8; ++j) acc[j] *= t0[j];
}

__device__ __forceinline__ void rbf16(const uint4* __restrict__ lcq,
                                      const float* __restrict__ ks,
                                      float xn, float yn, float zn, int cq, float* acc)
{
    const float interval = 2.0f / 63.0f;
    const float invi = 31.5f;
    float fc0 = fminf(fmaxf(floorf((xn + 1.0f) * invi), 0.0f), 62.0f);
    float fc1 = fminf(fmaxf(floorf((yn + 1.0f) * invi), 0.0f), 62.0f);
    float fc2 = fminf(fmaxf(floorf((zn + 1.0f) * invi), 0.0f), 62.0f);
    int c0 = (int)fc0, c1 = (int)fc1, c2 = (int)fc2;
    float dx0 = xn - (-1.0f + fc0 * interval), dx1 = dx0 - interval;
    float dy0 = yn - (-1.0f + fc1 * interval), dy1 = dy0 - interval;
    float dz0 = zn - (-1.0f + fc2 * interval), dz1 = dz0 - interval;
    int ibase = (c0 * 64 + c1) * 64 + c2;

    float phi[8]; int id[8];
    float sum = 0.0f;
#pragma unroll
    for (int k = 0; k < 8; ++k) {
        int i = (k >> 2) & 1, j = (k >> 1) & 1, l = k & 1;
        int idx = ibase + i * 4096 + j * 64 + l;
        id[k] = idx;
        float ddx = i ? dx1 : dx0;
        float ddy = j ? dy1 : dy0;
        float ddz = l ? dz1 : dz0;
        float dd = ddx * ddx + ddy * ddy + ddz * ddz;
        float s = ks[idx];
        float ph = __builtin_amdgcn_rcpf(fmaf(dd, s * s, 1.0f));
        phi[k] = ph;
        sum += ph;
    }
    float inv = __builtin_amdgcn_rcpf(sum + 1e-8f);
#pragma unroll
    for (int j = 0; j < 8; ++j) acc[j] = 0.0f;
#pragma unroll
    for (int k = 0; k < 8; ++k) {
        float w = phi[k] * inv;
        uint4 u = lcq[id[k] * 4 + cq];
        float v[8]; unpack8(u, v);
#pragma unroll
        for (int j = 0; j < 8; ++j) acc[j] = fmaf(w, v[j], acc[j]);
    }
}

// ---------------------------------------------------------------------------
// Main kernel (sorted path): block = 4 waves; all 4 waves cover the SAME 16
// points; wave role uniform (w0:R128, w1:R256, w2:R512, w3:RBF).
// lane = point(4b)*4 + cq(2b); each lane produces 8 channels.
// ---------------------------------------------------------------------------
__global__ __launch_bounds__(256) void field16_kernel(
    const uint4* __restrict__ tq0, const uint4* __restrict__ tq1, const uint4* __restrict__ tq2,
    const uint4* __restrict__ lcq,
    const float* __restrict__ ks, const float* __restrict__ kpb,
    const float4* __restrict__ sp, float* __restrict__ out, int N)
{
    const int wave = threadIdx.x >> 6;
    const int lane = threadIdx.x & 63;
    const int p    = lane >> 2;
    const int cq   = lane & 3;
    int bid = blockIdx.x;
    int nb = gridDim.x;
    if ((nb & 7) == 0) bid = (bid & 7) * (nb >> 3) + (bid >> 3);  // XCD chunking
    const int m = bid * 16 + p;
    if (m >= N) return;

    float4 q = sp[m];
    float xn = q.x, yn = q.y, zn = q.z;
    int n = __float_as_int(q.w);

    float acc[8];
    int base;
    if (wave == 0)      { base = 0;  plane_feat16<128>(tq0, xn, yn, zn, cq, acc); }
    else if (wave == 1) { base = 32; plane_feat16<256>(tq1, xn, yn, zn, cq, acc); }
    else if (wave == 2) { base = 64; plane_feat16<512>(tq2, xn, yn, zn, cq, acc); }
    else                { base = 96; rbf16(lcq, ks, xn, yn, zn, cq, acc); }

    const float* kb = kpb + base + cq * 8;
    float4 k0 = *(const float4*)kb;
    float4 k1 = *(const float4*)(kb + 4);
    float* o = out + (size_t)n * 128 + base + cq * 8;
    float4 r0; r0.x = acc[0] + k0.x; r0.y = acc[1] + k0.y; r0.z = acc[2] + k0.z; r0.w = acc[3] + k0.w;
    float4 r1; r1.x = acc[4] + k1.x; r1.y = acc[5] + k1.y; r1.z = acc[6] + k1.z; r1.w = acc[7] + k1.w;
    *(float4*)o = r0;
    *(float4*)(o + 4) = r1;
}

// ---------------------------------------------------------------------------
// Legacy helpers + field kernel (fallback paths, unchanged semantics).
// ---------------------------------------------------------------------------
template <int R>
__device__ __forceinline__ float2 sample_tp(const bf162* __restrict__ tp,
                                            float cx, float cy, int cpair)
{
    float gx = (cx + 1.0f) * (0.5f * (float)(R - 1));
    float gy = (cy + 1.0f) * (0.5f * (float)(R - 1));
    float fx = fminf(fmaxf(floorf(gx), 0.0f), (float)(R - 2));
    float fy = fminf(fmaxf(floorf(gy), 0.0f), (float)(R - 2));
    float wx = gx - fx, wy = gy - fy;
    int ix = (int)fx, iy = (int)fy;
    int i00 = (iy * R + ix) * 16 + cpair;
    int i10 = i00 + R * 16;
    bf162 v00 = tp[i00];
    bf162 v01 = tp[i00 + 16];
    bf162 v10 = tp[i10];
    bf162 v11 = tp[i10 + 16];
    float w11 = wx * wy;
    float w01 = wx - w11;
    float w10 = wy - w11;
    float w00 = 1.0f - wx - wy + w11;
    float2 r;
    r.x = __bfloat162float(v00.x) * w00 + __bfloat162float(v01.x) * w01
        + __bfloat162float(v10.x) * w10 + __bfloat162float(v11.x) * w11;
    r.y = __bfloat162float(v00.y) * w00 + __bfloat162float(v01.y) * w01
        + __bfloat162float(v10.y) * w10 + __bfloat162float(v11.y) * w11;
    return r;
}

template <int R>
__device__ __forceinline__ float2 plane_feat(const bf162* __restrict__ tp,
                                             float xn, float yn, float zn, int cpair)
{
    const int ps = R * R * 16;
    float2 a = sample_tp<R>(tp,          xn, yn, cpair);
    float2 b = sample_tp<R>(tp + ps,     xn, zn, cpair);
    float2 c = sample_tp<R>(tp + 2 * ps, yn, zn, cpair);
    float2 r; r.x = a.x * b.x * c.x; r.y = a.y * b.y * c.y;
    return r;
}

__device__ __forceinline__ float2 sample_f32(const float* __restrict__ pl, int R,
                                             float cx, float cy, int ch)
{
    float gx = (cx + 1.0f) * 0.5f * (float)(R - 1);
    float gy = (cy + 1.0f) * 0.5f * (float)(R - 1);
    float fx = fminf(fmaxf(floorf(gx), 0.0f), (float)(R - 2));
    float fy = fminf(fmaxf(floorf(gy), 0.0f), (float)(R - 2));
    float wx = gx - fx, wy = gy - fy;
    int ix = (int)fx, iy = (int)fy;
    float w11 = wx * wy, w01 = wx - w11, w10 = wy - w11, w00 = 1.0f - wx - wy + w11;
    size_t HW = (size_t)R * R;
    const float* q0 = pl + (size_t)ch * HW + (size_t)iy * R + ix;
    const float* q1 = q0 + HW;
    float2 r;
    r.x = q0[0] * w00 + q0[1] * w01 + q0[R] * w10 + q0[R + 1] * w11;
    r.y = q1[0] * w00 + q1[1] * w01 + q1[R] * w10 + q1[R + 1] * w11;
    return r;
}

template <bool TP>
__device__ __forceinline__ float2 rbf_feat(const bf162* __restrict__ lc0b,
                                           const float* __restrict__ lc0f,
                                           const float* __restrict__ ks,
                                           float xn, float yn, float zn, int cpair)
{
    const float interval = 2.0f / 63.0f;
    const float invi = 31.5f;
    float fc0 = fminf(fmaxf(floorf((xn + 1.0f) * invi), 0.0f), 62.0f);
    float fc1 = fminf(fmaxf(floorf((yn + 1.0f) * invi), 0.0f), 62.0f);
    float fc2 = fminf(fmaxf(floorf((zn + 1.0f) * invi), 0.0f), 62.0f);
    int c0 = (int)fc0, c1 = (int)fc1, c2 = (int)fc2;
    float dx0 = xn - (-1.0f + fc0 * interval), dx1 = dx0 - interval;
    float dy0 = yn - (-1.0f + fc1 * interval), dy1 = dy0 - interval;
    float dz0 = zn - (-1.0f + fc2 * interval), dz1 = dz0 - interval;
    int ibase = (c0 * 64 + c1) * 64 + c2;

    float phi[8]; int id[8];
    float sum = 0.0f;
#pragma unroll
    for (int k = 0; k < 8; ++k) {
        int i = (k >> 2) & 1, j = (k >> 1) & 1, l = k & 1;
        int idx = ibase + i * 4096 + j * 64 + l;
        id[k] = idx;
        float ddx = i ? dx1 : dx0;
        float ddy = j ? dy1 : dy0;
        float ddz = l ? dz1 : dz0;
        float dd = ddx * ddx + ddy * ddy + ddz * ddz;
        float s = ks[idx];
        float ph = __builtin_amdgcn_rcpf(fmaf(dd, s * s, 1.0f));
        phi[k] = ph;
        sum += ph;
    }
    float inv = __builtin_amdgcn_rcpf(sum + 1e-8f);
    float ax = 0.0f, ay = 0.0f;
#pragma unroll
    for (int k = 0; k < 8; ++k) {
        float w = phi[k] * inv;
        float vx, vy;
        if (TP) {
            bf162 v = lc0b[id[k] * 16 + cpair];
            vx = __bfloat162float(v.x); vy = __bfloat162float(v.y);
        } else {
            const float* cp = lc0f + (size_t)id[k] * 32 + 2 * cpair;
            vx = cp[0]; vy = cp[1];
        }
        ax = fmaf(w, vx, ax);
        ay = fmaf(w, vy, ay);
    }
    float2 r; r.x = ax; r.y = ay;
    return r;
}

template <bool TP>
__global__ __launch_bounds__(256) void field_legacy_kernel(
    const float* __restrict__ pts, const float* __restrict__ aabb,
    const float* __restrict__ p00, const float* __restrict__ p01, const float* __restrict__ p02,
    const float* __restrict__ p10, const float* __restrict__ p11, const float* __restrict__ p12,
    const float* __restrict__ p20, const float* __restrict__ p21, const float* __restrict__ p22,
    const bf162* __restrict__ tp0, const bf162* __restrict__ tp1, const bf162* __restrict__ tp2,
    const bf162* __restrict__ lc0b, const float* __restrict__ lc0f,
    const float* __restrict__ ks, const float* __restrict__ kpb,
    float* __restrict__ out, int N)
{
    const int wave  = threadIdx.x >> 6;
    const int lane  = threadIdx.x & 63;
    const int p     = lane >> 4;
    const int cpair = lane & 15;
    const int n = blockIdx.x * 4 + p;
    if (n >= N) return;

    float px = pts[3 * (size_t)n + 0];
    float py = pts[3 * (size_t)n + 1];
    float pz = pts[3 * (size_t)n + 2];
    float xn = (px - aabb[0]) * (2.0f / (aabb[3] - aabb[0])) - 1.0f;
    float yn = (py - aabb[1]) * (2.0f / (aabb[4] - aabb[1])) - 1.0f;
    float zn = (pz - aabb[2]) * (2.0f / (aabb[5] - aabb[2])) - 1.0f;

    float2 val;
    int f;
    if (wave == 0) {
        if (TP) val = plane_feat<128>(tp0, xn, yn, zn, cpair);
        else {
            float2 a = sample_f32(p00, 128, xn, yn, 2 * cpair);
            float2 b = sample_f32(p01, 128, xn, zn, 2 * cpair);
            float2 c = sample_f32(p02, 128, yn, zn, 2 * cpair);
            val.x = a.x * b.x * c.x; val.y = a.y * b.y * c.y;
        }
        f = 2 * cpair;
    } else if (wave == 1) {
        if (TP) val = plane_feat<256>(tp1, xn, yn, zn, cpair);
        else {
            float2 a = sample_f32(p10, 256, xn, yn, 2 * cpair);
            float2 b = sample_f32(p11, 256, xn, zn, 2 * cpair);
            float2 c = sample_f32(p12, 256, yn, zn, 2 * cpair);
            val.x = a.x * b.x * c.x; val.y = a.y * b.y * c.y;
        }
        f = 32 + 2 * cpair;
    } else if (wave == 2) {
        if (TP) val = plane_feat<512>(tp2, xn, yn, zn, cpair);
        else {
            float2 a = sample_f32(p20, 512, xn, yn, 2 * cpair);
            float2 b = sample_f32(p21, 512, xn, zn, 2 * cpair);
            float2 c = sample_f32(p22, 512, yn, zn, 2 * cpair);
            val.x = a.x * b.x * c.x; val.y = a.y * b.y * c.y;
        }
        f = 64 + 2 * cpair;
    } else {
        val = rbf_feat<TP>(lc0b, lc0f, ks, xn, yn, zn, cpair);
        f = 96 + 2 * cpair;
    }

    val.x += kpb[f];
    val.y += kpb[f + 1];
    *(float2*)(out + (size_t)n * 128 + f) = val;
}

// ---------------------------------------------------------------------------
extern "C" void kernel_launch(void* const* d_in, const int* in_sizes, int n_in,
                              void* d_out, int out_size, void* d_ws, size_t ws_size,
                              hipStream_t stream)
{
    const float* pts  = (const float*)d_in[0];
    const float* aabb = (const float*)d_in[1];
    const float* pl[9];
    for (int i = 0; i < 9; ++i) pl[i] = (const float*)d_in[2 + i];
    const float* lc0 = (const float*)d_in[11];
    const float* ks  = (const float*)d_in[12];
    const float* kpb = (const float*)d_in[13];
    float* out = (float*)d_out;
    const int N = in_sizes[0] / 3;

    const size_t needTP = (3 * (S0 + S1 + S2) + LCN) * sizeof(bf16);   // 82.8 MB
    const size_t cntOff = needTP;                                      // 16B aligned
    const size_t spOff  = cntOff + (size_t)NBUCKETS * 4;               // 16B aligned
    const size_t needSort = spOff + (size_t)N * 16;

    bf16* w    = (bf16*)d_ws;
    bf16* tp0  = w;
    bf16* tp1  = tp0 + 3 * S0;
    bf16* tp2  = tp1 + 3 * S1;
    bf16* lc0b = tp2 + 3 * S2;
    unsigned int* counts = (unsigned int*)((char*)d_ws + cntOff);
    float4* sp = (float4*)((char*)d_ws + spOff);

    const bool useTP   = (d_ws != nullptr) && (ws_size >= needTP);
    const bool useSort = (d_ws != nullptr) && (ws_size >= needSort);

    if (useSort) {
        const int g4 = (N + 1023) / 1024;            // 4 points per thread
        zero_counts_kernel<<<NBUCKETS / 256, 256, 0, stream>>>(counts);
        hist_kernel<<<g4, 256, 0, stream>>>(pts, aabb, counts, N);
        transpose_kernel<<<TPLANES, 256, 0, stream>>>(
            pl[0], pl[1], pl[2], pl[3], pl[4], pl[5], pl[6], pl[7], pl[8],
            tp0, tp1, tp2);
        lc0cast_kernel<<<TLC2, 256, 0, stream>>>(lc0, lc0b);
        scan_kernel<<<1, 1024, 0, stream>>>(counts);
        scatter_kernel<<<g4, 256, 0, stream>>>(pts, aabb, counts, sp, N);
        const int blocks16 = (N + 15) / 16;
        field16_kernel<<<blocks16, 256, 0, stream>>>(
            (const uint4*)tp0, (const uint4*)tp1, (const uint4*)tp2,
            (const uint4*)lc0b, ks, kpb, sp, out, N);
    } else if (useTP) {
        transpose_kernel<<<TPLANES, 256, 0, stream>>>(
            pl[0], pl[1], pl[2], pl[3], pl[4], pl[5], pl[6], pl[7], pl[8],
            tp0, tp1, tp2);
        lc0cast_kernel<<<TLC2, 256, 0, stream>>>(lc0, lc0b);
        field_legacy_kernel<true><<<(N + 3) / 4, 256, 0, stream>>>(
            pts, aabb, pl[0], pl[1], pl[2], pl[3], pl[4], pl[5], pl[6], pl[7], pl[8],
            (const bf162*)tp0, (const bf162*)tp1, (const bf162*)tp2,
            (const bf162*)lc0b, lc0, ks, kpb, out, N);
    } else {
        field_legacy_kernel<false><<<(N + 3) / 4, 256, 0, stream>>>(
            pts, aabb, pl[0], pl[1], pl[2], pl[3], pl[4], pl[5], pl[6], pl[7], pl[8],
            (const bf162*)d_ws, (const bf162*)d_ws, (const bf162*)d_ws,
            (const bf162*)d_ws, lc0, ks, kpb, out, N);
    }
}

// Round 5
// 577.552 us; speedup vs baseline: 1.0459x; 1.0166x over previous
//
#include <hip/hip_runtime.h>
#include <hip/hip_bf16.h>
#include <stdint.h>

typedef __hip_bfloat16 bf16;
typedef __hip_bfloat162 bf162;

// ---- table sizes (elements) ----
#define S0 ((size_t)(128*128*32))
#define S1 ((size_t)(256*256*32))
#define S2 ((size_t)(512*512*32))
#define LCN ((size_t)(64*64*64*32))

// ---- pre-pass tile bookkeeping: 64-position transpose tiles ----
#define T128 (128*128/64)            // 256
#define T256 (256*256/64)            // 1024
#define T512 (512*512/64)            // 4096
#define TPLANES (3*T128 + 3*T256 + 3*T512)   // 16128
#define TLC2 ((int)(LCN/2048))                // 4096 (256 thr x 8 elems)

// ---- spatial sort ----
#define NBUCKETS 32768               // 32^3 morton cells

__device__ __forceinline__ uint32_t mpart(uint32_t x)
{
    x = (x | (x << 16)) & 0x030000FFu;
    x = (x | (x << 8))  & 0x0300F00Fu;
    x = (x | (x << 4))  & 0x030C30C3u;
    x = (x | (x << 2))  & 0x09249249u;
    return x;
}

__device__ __forceinline__ uint32_t bucket_of(float xn, float yn, float zn)
{
    float bx = fminf(fmaxf(floorf((xn + 1.0f) * 16.0f), 0.0f), 31.0f);
    float by = fminf(fmaxf(floorf((yn + 1.0f) * 16.0f), 0.0f), 31.0f);
    float bz = fminf(fmaxf(floorf((zn + 1.0f) * 16.0f), 0.0f), 31.0f);
    return mpart((uint32_t)bx) | (mpart((uint32_t)by) << 1) | (mpart((uint32_t)bz) << 2);
}

__device__ __forceinline__ uint32_t pack2(float a, float b)
{
    union { bf162 h; uint32_t u; } cv;
    cv.h = __halves2bfloat162(__float2bfloat16(a), __float2bfloat16(b));
    return cv.u;
}

__device__ __forceinline__ void unpack8(uint4 u, float* f)
{
    const bf162* h = (const bf162*)&u;
    f[0] = __bfloat162float(h[0].x); f[1] = __bfloat162float(h[0].y);
    f[2] = __bfloat162float(h[1].x); f[3] = __bfloat162float(h[1].y);
    f[4] = __bfloat162float(h[2].x); f[5] = __bfloat162float(h[2].y);
    f[6] = __bfloat162float(h[3].x); f[7] = __bfloat162float(h[3].y);
}

// ---------------------------------------------------------------------------
__global__ __launch_bounds__(256) void zero_counts_kernel(unsigned int* __restrict__ counts)
{
    counts[blockIdx.x * 256 + threadIdx.x] = 0u;
}

// ---------------------------------------------------------------------------
// Fused pre-pass: 9 plane transposes + lc0 cast + point histogram.
// Block ranges: [0,TPLANES) transpose | [TPLANES,TPLANES+TLC2) lc0 |
//               [TPLANES+TLC2, ...) histogram (4 pts/thread).
// ---------------------------------------------------------------------------
__global__ __launch_bounds__(256) void prep_kernel(
    const float* __restrict__ p00, const float* __restrict__ p01, const float* __restrict__ p02,
    const float* __restrict__ p10, const float* __restrict__ p11, const float* __restrict__ p12,
    const float* __restrict__ p20, const float* __restrict__ p21, const float* __restrict__ p22,
    const float* __restrict__ lc0,
    bf16* __restrict__ tp0, bf16* __restrict__ tp1, bf16* __restrict__ tp2,
    bf16* __restrict__ lc0b,
    const float* __restrict__ pts, const float* __restrict__ aabb,
    unsigned int* __restrict__ counts, int N)
{
    const int b = blockIdx.x;
    const int tid = threadIdx.x;
    __shared__ float t[64 * 33];
    if (b < TPLANES) {
        const float* src; bf16* dst; int HW, tile;
        if (b < 3 * T128) {
            int pid = b >> 8; tile = b & (T128 - 1); HW = 128 * 128;
            src = pid == 0 ? p00 : (pid == 1 ? p01 : p02);
            dst = tp0 + (size_t)pid * S0;
        } else if (b < 3 * T128 + 3 * T256) {
            int bb = b - 3 * T128; int pid = bb >> 10; tile = bb & (T256 - 1); HW = 256 * 256;
            src = pid == 0 ? p10 : (pid == 1 ? p11 : p12);
            dst = tp1 + (size_t)pid * S1;
        } else {
            int bb = b - 3 * T128 - 3 * T256; int pid = bb >> 12; tile = bb & (T512 - 1); HW = 512 * 512;
            src = pid == 0 ? p20 : (pid == 1 ? p21 : p22);
            dst = tp2 + (size_t)pid * S2;
        }
        const int base = tile * 64;
#pragma unroll
        for (int i = 0; i < 2; ++i) {
            int linear = i * 256 + tid;              // [0,512)
            int ch = linear >> 4, pq = linear & 15;  // pq = pos quad
            float4 v = *(const float4*)(src + (size_t)ch * HW + base + pq * 4);
            t[(pq * 4 + 0) * 33 + ch] = v.x;
            t[(pq * 4 + 1) * 33 + ch] = v.y;
            t[(pq * 4 + 2) * 33 + ch] = v.z;
            t[(pq * 4 + 3) * 33 + ch] = v.w;
        }
        __syncthreads();
        {
            int pos = tid >> 2, chunk = tid & 3;
            const float* row = t + pos * 33 + chunk * 8;
            uint4 o;
            o.x = pack2(row[0], row[1]);
            o.y = pack2(row[2], row[3]);
            o.z = pack2(row[4], row[5]);
            o.w = pack2(row[6], row[7]);
            *(uint4*)(dst + (size_t)(base + pos) * 32 + chunk * 8) = o;
        }
    } else if (b < TPLANES + TLC2) {
        size_t off = (size_t)(b - TPLANES) * 2048 + (size_t)tid * 8;
        float4 v0 = *(const float4*)(lc0 + off);
        float4 v1 = *(const float4*)(lc0 + off + 4);
        uint4 o;
        o.x = pack2(v0.x, v0.y);
        o.y = pack2(v0.z, v0.w);
        o.z = pack2(v1.x, v1.y);
        o.w = pack2(v1.z, v1.w);
        *(uint4*)(lc0b + off) = o;
    } else {
        int g = (b - TPLANES - TLC2) * 256 + tid;
        int b0 = g * 4;
        if (b0 >= N) return;
        float a0 = aabb[0], a1 = aabb[1], a2 = aabb[2];
        float sx = 2.0f / (aabb[3] - a0);
        float sy = 2.0f / (aabb[4] - a1);
        float sz = 2.0f / (aabb[5] - a2);
        if (b0 + 3 < N) {
            const float4* p4 = (const float4*)(pts + (size_t)b0 * 3);
            float4 A = p4[0], B = p4[1], C = p4[2];
            float px[4] = {A.x, A.w, B.z, C.y};
            float py[4] = {A.y, B.x, B.w, C.z};
            float pz[4] = {A.z, B.y, C.x, C.w};
#pragma unroll
            for (int k = 0; k < 4; ++k) {
                float xn = (px[k] - a0) * sx - 1.0f;
                float yn = (py[k] - a1) * sy - 1.0f;
                float zn = (pz[k] - a2) * sz - 1.0f;
                atomicAdd(&counts[bucket_of(xn, yn, zn)], 1u);
            }
        } else {
            for (int i = b0; i < N; ++i) {
                float xn = (pts[3 * (size_t)i + 0] - a0) * sx - 1.0f;
                float yn = (pts[3 * (size_t)i + 1] - a1) * sy - 1.0f;
                float zn = (pts[3 * (size_t)i + 2] - a2) * sz - 1.0f;
                atomicAdd(&counts[bucket_of(xn, yn, zn)], 1u);
            }
        }
    }
}

// ---------------------------------------------------------------------------
// Exclusive prefix sum over NBUCKETS=32768 counters, single block.
// ---------------------------------------------------------------------------
__global__ __launch_bounds__(1024) void scan_kernel(unsigned int* __restrict__ counts)
{
    __shared__ unsigned int sums[1024];
    const int t = threadIdx.x;
    unsigned int local[32];
    unsigned int s = 0;
#pragma unroll
    for (int i = 0; i < 32; ++i) { local[i] = counts[t * 32 + i]; s += local[i]; }
    sums[t] = s;
    __syncthreads();
    for (int off = 1; off < 1024; off <<= 1) {
        unsigned int v = (t >= off) ? sums[t - off] : 0u;
        __syncthreads();
        sums[t] += v;
        __syncthreads();
    }
    unsigned int run = sums[t] - s;                  // exclusive base for this chunk
#pragma unroll
    for (int i = 0; i < 32; ++i) { unsigned int c = local[i]; counts[t * 32 + i] = run; run += c; }
}

// ---------------------------------------------------------------------------
// Scatter: 4 points per thread; sp[pos] = (xn, yn, zn, bitcast(n)).
// ---------------------------------------------------------------------------
__global__ __launch_bounds__(256) void scatter_kernel(
    const float* __restrict__ pts, const float* __restrict__ aabb,
    unsigned int* __restrict__ offsets, float4* __restrict__ sp, int N)
{
    int g = blockIdx.x * 256 + threadIdx.x;
    int b0 = g * 4;
    if (b0 >= N) return;
    float a0 = aabb[0], a1 = aabb[1], a2 = aabb[2];
    float sx = 2.0f / (aabb[3] - a0);
    float sy = 2.0f / (aabb[4] - a1);
    float sz = 2.0f / (aabb[5] - a2);
    if (b0 + 3 < N) {
        const float4* p4 = (const float4*)(pts + (size_t)b0 * 3);
        float4 A = p4[0], B = p4[1], C = p4[2];
        float px[4] = {A.x, A.w, B.z, C.y};
        float py[4] = {A.y, B.x, B.w, C.z};
        float pz[4] = {A.z, B.y, C.x, C.w};
#pragma unroll
        for (int k = 0; k < 4; ++k) {
            float xn = (px[k] - a0) * sx - 1.0f;
            float yn = (py[k] - a1) * sy - 1.0f;
            float zn = (pz[k] - a2) * sz - 1.0f;
            unsigned int pos = atomicAdd(&offsets[bucket_of(xn, yn, zn)], 1u);
            float4 v; v.x = xn; v.y = yn; v.z = zn; v.w = __int_as_float(b0 + k);
            sp[pos] = v;
        }
    } else {
        for (int i = b0; i < N; ++i) {
            float xn = (pts[3 * (size_t)i + 0] - a0) * sx - 1.0f;
            float yn = (pts[3 * (size_t)i + 1] - a1) * sy - 1.0f;
            float zn = (pts[3 * (size_t)i + 2] - a2) * sz - 1.0f;
            unsigned int pos = atomicAdd(&offsets[bucket_of(xn, yn, zn)], 1u);
            float4 v; v.x = xn; v.y = yn; v.z = zn; v.w = __int_as_float(i);
            sp[pos] = v;
        }
    }
}

// ---------------------------------------------------------------------------
// field16 helpers: 16 points/wave, 8 channels/lane, 16B corner gathers.
// Loads for all samples are issued up-front for latency hiding.
// ---------------------------------------------------------------------------
template <int R>
__device__ __forceinline__ void samp_addr(float cx, float cy, int cq,
                                          int& t00, float4& w)
{
    float gx = (cx + 1.0f) * (0.5f * (float)(R - 1));
    float gy = (cy + 1.0f) * (0.5f * (float)(R - 1));
    float fx = fminf(fmaxf(floorf(gx), 0.0f), (float)(R - 2));
    float fy = fminf(fmaxf(floorf(gy), 0.0f), (float)(R - 2));
    float wx = gx - fx, wy = gy - fy;
    int ix = (int)fx, iy = (int)fy;
    t00 = (iy * R + ix) * 4 + cq;
    float w11 = wx * wy;
    w.x = 1.0f - wx - wy + w11;   // w00
    w.y = wx - w11;               // w01
    w.z = wy - w11;               // w10
    w.w = w11;
}

__device__ __forceinline__ void lerp8(uint4 u00, uint4 u01, uint4 u10, uint4 u11,
                                      float4 w, float* o)
{
    float a[8], b[8], c[8], d[8];
    unpack8(u00, a); unpack8(u01, b); unpack8(u10, c); unpack8(u11, d);
#pragma unroll
    for (int j = 0; j < 8; ++j)
        o[j] = fmaf(d[j], w.w, fmaf(c[j], w.z, fmaf(b[j], w.y, a[j] * w.x)));
}

template <int R>
__device__ __forceinline__ void plane_feat16(const uint4* __restrict__ tq,
                                             float xn, float yn, float zn, int cq, float* acc)
{
    const int ps = R * R * 4;                        // one plane in uint4 units
    int tA, tB, tC; float4 wA, wB, wC;
    samp_addr<R>(xn, yn, cq, tA, wA);                // comb (0,1)
    samp_addr<R>(xn, zn, cq, tB, wB);                // comb (0,2)
    samp_addr<R>(yn, zn, cq, tC, wC);                // comb (1,2)
    const uint4* qA = tq;
    const uint4* qB = tq + ps;
    const uint4* qC = tq + 2 * ps;
    // issue all 12 independent loads back-to-back
    uint4 a00 = qA[tA],         a01 = qA[tA + 4];
    uint4 a10 = qA[tA + R * 4], a11 = qA[tA + R * 4 + 4];
    uint4 b00 = qB[tB],         b01 = qB[tB + 4];
    uint4 b10 = qB[tB + R * 4], b11 = qB[tB + R * 4 + 4];
    uint4 c00 = qC[tC],         c01 = qC[tC + 4];
    uint4 c10 = qC[tC + R * 4], c11 = qC[tC + R * 4 + 4];
    float sA[8], sB[8], sC[8];
    lerp8(a00, a01, a10, a11, wA, sA);
    lerp8(b00, b01, b10, b11, wB, sB);
    lerp8(c00, c01, c10, c11, wC, sC);
#pragma unroll
    for (int j = 0; j < 8; ++j) acc[j] = sA[j] * sB[j] * sC[j];
}

__device__ __forceinline__ void rbf16(const uint4* __restrict__ lcq,
                                      const float* __restrict__ ks,
                                      float xn, float yn, float zn, int cq, float* acc)
{
    const float interval = 2.0f / 63.0f;
    const float invi = 31.5f;
    float fc0 = fminf(fmaxf(floorf((xn + 1.0f) * invi), 0.0f), 62.0f);
    float fc1 = fminf(fmaxf(floorf((yn + 1.0f) * invi), 0.0f), 62.0f);
    float fc2 = fminf(fmaxf(floorf((zn + 1.0f) * invi), 0.0f), 62.0f);
    int c0 = (int)fc0, c1 = (int)fc1, c2 = (int)fc2;
    float dx0 = xn - (-1.0f + fc0 * interval), dx1 = dx0 - interval;
    float dy0 = yn - (-1.0f + fc1 * interval), dy1 = dy0 - interval;
    float dz0 = zn - (-1.0f + fc2 * interval), dz1 = dz0 - interval;
    int ibase = (c0 * 64 + c1) * 64 + c2;

    int id[8];
#pragma unroll
    for (int k = 0; k < 8; ++k) {
        int i = (k >> 2) & 1, j = (k >> 1) & 1, l = k & 1;
        id[k] = ibase + i * 4096 + j * 64 + l;
    }
    // issue all 16 independent loads up-front
    float s0 = ks[id[0]], s1 = ks[id[1]], s2 = ks[id[2]], s3 = ks[id[3]];
    float s4 = ks[id[4]], s5 = ks[id[5]], s6 = ks[id[6]], s7 = ks[id[7]];
    uint4 u0 = lcq[id[0] * 4 + cq], u1 = lcq[id[1] * 4 + cq];
    uint4 u2 = lcq[id[2] * 4 + cq], u3 = lcq[id[3] * 4 + cq];
    uint4 u4 = lcq[id[4] * 4 + cq], u5 = lcq[id[5] * 4 + cq];
    uint4 u6 = lcq[id[6] * 4 + cq], u7 = lcq[id[7] * 4 + cq];

    float sarr[8] = {s0, s1, s2, s3, s4, s5, s6, s7};
    float phi[8];
    float sum = 0.0f;
#pragma unroll
    for (int k = 0; k < 8; ++k) {
        int i = (k >> 2) & 1, j = (k >> 1) & 1, l = k & 1;
        float ddx = i ? dx1 : dx0;
        float ddy = j ? dy1 : dy0;
        float ddz = l ? dz1 : dz0;
        float dd = ddx * ddx + ddy * ddy + ddz * ddz;
        float s = sarr[k];
        float ph = __builtin_amdgcn_rcpf(fmaf(dd, s * s, 1.0f));
        phi[k] = ph;
        sum += ph;
    }
    float inv = __builtin_amdgcn_rcpf(sum + 1e-8f);
#pragma unroll
    for (int j = 0; j < 8; ++j) acc[j] = 0.0f;
    uint4 uarr[8] = {u0, u1, u2, u3, u4, u5, u6, u7};
#pragma unroll
    for (int k = 0; k < 8; ++k) {
        float w = phi[k] * inv;
        float v[8]; unpack8(uarr[k], v);
#pragma unroll
        for (int j = 0; j < 8; ++j) acc[j] = fmaf(w, v[j], acc[j]);
    }
}

// ---------------------------------------------------------------------------
// Main kernel (sorted path): block = 4 waves; all 4 waves cover the SAME 16
// points; wave role uniform (w0:R128, w1:R256, w2:R512, w3:RBF).
// lane = point(4b)*4 + cq(2b); each lane produces 8 channels.
// ---------------------------------------------------------------------------
__global__ __launch_bounds__(256) void field16_kernel(
    const uint4* __restrict__ tq0, const uint4* __restrict__ tq1, const uint4* __restrict__ tq2,
    const uint4* __restrict__ lcq,
    const float* __restrict__ ks, const float* __restrict__ kpb,
    const float4* __restrict__ sp, float* __restrict__ out, int N)
{
    const int wave = threadIdx.x >> 6;
    const int lane = threadIdx.x & 63;
    const int p    = lane >> 2;
    const int cq   = lane & 3;
    int bid = blockIdx.x;
    int nb = gridDim.x;
    if ((nb & 7) == 0) bid = (bid & 7) * (nb >> 3) + (bid >> 3);  // XCD chunking
    const int m = bid * 16 + p;
    if (m >= N) return;

    float4 q = sp[m];
    float xn = q.x, yn = q.y, zn = q.z;
    int n = __float_as_int(q.w);

    float acc[8];
    int base;
    if (wave == 0)      { base = 0;  plane_feat16<128>(tq0, xn, yn, zn, cq, acc); }
    else if (wave == 1) { base = 32; plane_feat16<256>(tq1, xn, yn, zn, cq, acc); }
    else if (wave == 2) { base = 64; plane_feat16<512>(tq2, xn, yn, zn, cq, acc); }
    else                { base = 96; rbf16(lcq, ks, xn, yn, zn, cq, acc); }

    const float* kb = kpb + base + cq * 8;
    float4 k0 = *(const float4*)kb;
    float4 k1 = *(const float4*)(kb + 4);
    float* o = out + (size_t)n * 128 + base + cq * 8;
    float4 r0; r0.x = acc[0] + k0.x; r0.y = acc[1] + k0.y; r0.z = acc[2] + k0.z; r0.w = acc[3] + k0.w;
    float4 r1; r1.x = acc[4] + k1.x; r1.y = acc[5] + k1.y; r1.z = acc[6] + k1.z; r1.w = acc[7] + k1.w;
    *(float4*)o = r0;
    *(float4*)(o + 4) = r1;
}

// ---------------------------------------------------------------------------
// Legacy helpers + field kernel (fallback paths, unchanged semantics).
// ---------------------------------------------------------------------------
template <int R>
__device__ __forceinline__ float2 sample_tp(const bf162* __restrict__ tp,
                                            float cx, float cy, int cpair)
{
    float gx = (cx + 1.0f) * (0.5f * (float)(R - 1));
    float gy = (cy + 1.0f) * (0.5f * (float)(R - 1));
    float fx = fminf(fmaxf(floorf(gx), 0.0f), (float)(R - 2));
    float fy = fminf(fmaxf(floorf(gy), 0.0f), (float)(R - 2));
    float wx = gx - fx, wy = gy - fy;
    int ix = (int)fx, iy = (int)fy;
    int i00 = (iy * R + ix) * 16 + cpair;
    int i10 = i00 + R * 16;
    bf162 v00 = tp[i00];
    bf162 v01 = tp[i00 + 16];
    bf162 v10 = tp[i10];
    bf162 v11 = tp[i10 + 16];
    float w11 = wx * wy;
    float w01 = wx - w11;
    float w10 = wy - w11;
    float w00 = 1.0f - wx - wy + w11;
    float2 r;
    r.x = __bfloat162float(v00.x) * w00 + __bfloat162float(v01.x) * w01
        + __bfloat162float(v10.x) * w10 + __bfloat162float(v11.x) * w11;
    r.y = __bfloat162float(v00.y) * w00 + __bfloat162float(v01.y) * w01
        + __bfloat162float(v10.y) * w10 + __bfloat162float(v11.y) * w11;
    return r;
}

template <int R>
__device__ __forceinline__ float2 plane_feat(const bf162* __restrict__ tp,
                                             float xn, float yn, float zn, int cpair)
{
    const int ps = R * R * 16;
    float2 a = sample_tp<R>(tp,          xn, yn, cpair);
    float2 b = sample_tp<R>(tp + ps,     xn, zn, cpair);
    float2 c = sample_tp<R>(tp + 2 * ps, yn, zn, cpair);
    float2 r; r.x = a.x * b.x * c.x; r.y = a.y * b.y * c.y;
    return r;
}

__device__ __forceinline__ float2 sample_f32(const float* __restrict__ pl, int R,
                                             float cx, float cy, int ch)
{
    float gx = (cx + 1.0f) * 0.5f * (float)(R - 1);
    float gy = (cy + 1.0f) * 0.5f * (float)(R - 1);
    float fx = fminf(fmaxf(floorf(gx), 0.0f), (float)(R - 2));
    float fy = fminf(fmaxf(floorf(gy), 0.0f), (float)(R - 2));
    float wx = gx - fx, wy = gy - fy;
    int ix = (int)fx, iy = (int)fy;
    float w11 = wx * wy, w01 = wx - w11, w10 = wy - w11, w00 = 1.0f - wx - wy + w11;
    size_t HW = (size_t)R * R;
    const float* q0 = pl + (size_t)ch * HW + (size_t)iy * R + ix;
    const float* q1 = q0 + HW;
    float2 r;
    r.x = q0[0] * w00 + q0[1] * w01 + q0[R] * w10 + q0[R + 1] * w11;
    r.y = q1[0] * w00 + q1[1] * w01 + q1[R] * w10 + q1[R + 1] * w11;
    return r;
}

template <bool TP>
__device__ __forceinline__ float2 rbf_feat(const bf162* __restrict__ lc0b,
                                           const float* __restrict__ lc0f,
                                           const float* __restrict__ ks,
                                           float xn, float yn, float zn, int cpair)
{
    const float interval = 2.0f / 63.0f;
    const float invi = 31.5f;
    float fc0 = fminf(fmaxf(floorf((xn + 1.0f) * invi), 0.0f), 62.0f);
    float fc1 = fminf(fmaxf(floorf((yn + 1.0f) * invi), 0.0f), 62.0f);
    float fc2 = fminf(fmaxf(floorf((zn + 1.0f) * invi), 0.0f), 62.0f);
    int c0 = (int)fc0, c1 = (int)fc1, c2 = (int)fc2;
    float dx0 = xn - (-1.0f + fc0 * interval), dx1 = dx0 - interval;
    float dy0 = yn - (-1.0f + fc1 * interval), dy1 = dy0 - interval;
    float dz0 = zn - (-1.0f + fc2 * interval), dz1 = dz0 - interval;
    int ibase = (c0 * 64 + c1) * 64 + c2;

    float phi[8]; int id[8];
    float sum = 0.0f;
#pragma unroll
    for (int k = 0; k < 8; ++k) {
        int i = (k >> 2) & 1, j = (k >> 1) & 1, l = k & 1;
        int idx = ibase + i * 4096 + j * 64 + l;
        id[k] = idx;
        float ddx = i ? dx1 : dx0;
        float ddy = j ? dy1 : dy0;
        float ddz = l ? dz1 : dz0;
        float dd = ddx * ddx + ddy * ddy + ddz * ddz;
        float s = ks[idx];
        float ph = __builtin_amdgcn_rcpf(fmaf(dd, s * s, 1.0f));
        phi[k] = ph;
        sum += ph;
    }
    float inv = __builtin_amdgcn_rcpf(sum + 1e-8f);
    float ax = 0.0f, ay = 0.0f;
#pragma unroll
    for (int k = 0; k < 8; ++k) {
        float w = phi[k] * inv;
        float vx, vy;
        if (TP) {
            bf162 v = lc0b[id[k] * 16 + cpair];
            vx = __bfloat162float(v.x); vy = __bfloat162float(v.y);
        } else {
            const float* cp = lc0f + (size_t)id[k] * 32 + 2 * cpair;
            vx = cp[0]; vy = cp[1];
        }
        ax = fmaf(w, vx, ax);
        ay = fmaf(w, vy, ay);
    }
    float2 r; r.x = ax; r.y = ay;
    return r;
}

template <bool TP>
__global__ __launch_bounds__(256) void field_legacy_kernel(
    const float* __restrict__ pts, const float* __restrict__ aabb,
    const float* __restrict__ p00, const float* __restrict__ p01, const float* __restrict__ p02,
    const float* __restrict__ p10, const float* __restrict__ p11, const float* __restrict__ p12,
    const float* __restrict__ p20, const float* __restrict__ p21, const float* __restrict__ p22,
    const bf162* __restrict__ tp0, const bf162* __restrict__ tp1, const bf162* __restrict__ tp2,
    const bf162* __restrict__ lc0b, const float* __restrict__ lc0f,
    const float* __restrict__ ks, const float* __restrict__ kpb,
    float* __restrict__ out, int N)
{
    const int wave  = threadIdx.x >> 6;
    const int lane  = threadIdx.x & 63;
    const int p     = lane >> 4;
    const int cpair = lane & 15;
    const int n = blockIdx.x * 4 + p;
    if (n >= N) return;

    float px = pts[3 * (size_t)n + 0];
    float py = pts[3 * (size_t)n + 1];
    float pz = pts[3 * (size_t)n + 2];
    float xn = (px - aabb[0]) * (2.0f / (aabb[3] - aabb[0])) - 1.0f;
    float yn = (py - aabb[1]) * (2.0f / (aabb[4] - aabb[1])) - 1.0f;
    float zn = (pz - aabb[2]) * (2.0f / (aabb[5] - aabb[2])) - 1.0f;

    float2 val;
    int f;
    if (wave == 0) {
        if (TP) val = plane_feat<128>(tp0, xn, yn, zn, cpair);
        else {
            float2 a = sample_f32(p00, 128, xn, yn, 2 * cpair);
            float2 b = sample_f32(p01, 128, xn, zn, 2 * cpair);
            float2 c = sample_f32(p02, 128, yn, zn, 2 * cpair);
            val.x = a.x * b.x * c.x; val.y = a.y * b.y * c.y;
        }
        f = 2 * cpair;
    } else if (wave == 1) {
        if (TP) val = plane_feat<256>(tp1, xn, yn, zn, cpair);
        else {
            float2 a = sample_f32(p10, 256, xn, yn, 2 * cpair);
            float2 b = sample_f32(p11, 256, xn, zn, 2 * cpair);
            float2 c = sample_f32(p12, 256, yn, zn, 2 * cpair);
            val.x = a.x * b.x * c.x; val.y = a.y * b.y * c.y;
        }
        f = 32 + 2 * cpair;
    } else if (wave == 2) {
        if (TP) val = plane_feat<512>(tp2, xn, yn, zn, cpair);
        else {
            float2 a = sample_f32(p20, 512, xn, yn, 2 * cpair);
            float2 b = sample_f32(p21, 512, xn, zn, 2 * cpair);
            float2 c = sample_f32(p22, 512, yn, zn, 2 * cpair);
            val.x = a.x * b.x * c.x; val.y = a.y * b.y * c.y;
        }
        f = 64 + 2 * cpair;
    } else {
        val = rbf_feat<TP>(lc0b, lc0f, ks, xn, yn, zn, cpair);
        f = 96 + 2 * cpair;
    }

    val.x += kpb[f];
    val.y += kpb[f + 1];
    *(float2*)(out + (size_t)n * 128 + f) = val;
}

// ---------------------------------------------------------------------------
extern "C" void kernel_launch(void* const* d_in, const int* in_sizes, int n_in,
                              void* d_out, int out_size, void* d_ws, size_t ws_size,
                              hipStream_t stream)
{
    const float* pts  = (const float*)d_in[0];
    const float* aabb = (const float*)d_in[1];
    const float* pl[9];
    for (int i = 0; i < 9; ++i) pl[i] = (const float*)d_in[2 + i];
    const float* lc0 = (const float*)d_in[11];
    const float* ks  = (const float*)d_in[12];
    const float* kpb = (const float*)d_in[13];
    float* out = (float*)d_out;
    const int N = in_sizes[0] / 3;

    const size_t needTP = (3 * (S0 + S1 + S2) + LCN) * sizeof(bf16);   // 82.8 MB
    const size_t cntOff = needTP;                                      // 16B aligned
    const size_t spOff  = cntOff + (size_t)NBUCKETS * 4;               // 16B aligned
    const size_t needSort = spOff + (size_t)N * 16;

    bf16* w    = (bf16*)d_ws;
    bf16* tp0  = w;
    bf16* tp1  = tp0 + 3 * S0;
    bf16* tp2  = tp1 + 3 * S1;
    bf16* lc0b = tp2 + 3 * S2;
    unsigned int* counts = (unsigned int*)((char*)d_ws + cntOff);
    float4* sp = (float4*)((char*)d_ws + spOff);

    const bool useTP   = (d_ws != nullptr) && (ws_size >= needTP);
    const bool useSort = (d_ws != nullptr) && (ws_size >= needSort);

    if (useSort) {
        const int g4 = (N + 1023) / 1024;            // 4 points per thread
        zero_counts_kernel<<<NBUCKETS / 256, 256, 0, stream>>>(counts);
        prep_kernel<<<TPLANES + TLC2 + g4, 256, 0, stream>>>(
            pl[0], pl[1], pl[2], pl[3], pl[4], pl[5], pl[6], pl[7], pl[8],
            lc0, tp0, tp1, tp2, lc0b, pts, aabb, counts, N);
        scan_kernel<<<1, 1024, 0, stream>>>(counts);
        scatter_kernel<<<g4, 256, 0, stream>>>(pts, aabb, counts, sp, N);
        const int blocks16 = (N + 15) / 16;
        field16_kernel<<<blocks16, 256, 0, stream>>>(
            (const uint4*)tp0, (const uint4*)tp1, (const uint4*)tp2,
            (const uint4*)lc0b, ks, kpb, sp, out, N);
    } else if (useTP) {
        prep_kernel<<<TPLANES + TLC2, 256, 0, stream>>>(
            pl[0], pl[1], pl[2], pl[3], pl[4], pl[5], pl[6], pl[7], pl[8],
            lc0, tp0, tp1, tp2, lc0b, pts, aabb, nullptr, 0);
        field_legacy_kernel<true><<<(N + 3) / 4, 256, 0, stream>>>(
            pts, aabb, pl[0], pl[1], pl[2], pl[3], pl[4], pl[5], pl[6], pl[7], pl[8],
            (const bf162*)tp0, (const bf162*)tp1, (const bf162*)tp2,
            (const bf162*)lc0b, lc0, ks, kpb, out, N);
    } else {
        field_legacy_kernel<false><<<(N + 3) / 4, 256, 0, stream>>>(
            pts, aabb, pl[0], pl[1], pl[2], pl[3], pl[4], pl[5], pl[6], pl[7], pl[8],
            (const bf162*)d_ws, (const bf162*)d_ws, (const bf162*)d_ws,
            (const bf162*)d_ws, lc0, ks, kpb, out, N);
    }
}